// Round 14
// baseline (576.240 us; speedup 1.0000x reference)
//
#include <hip/hip_runtime.h>
#include <cstdint>
#include <cstddef>

#define TT 4
#define BB 4
#define LL 1024
#define CC 256
#define HH 8
#define HD 32
#define NWIN 8
#define WIN 128
#define TOPKN 4
#define C3 768

// ---------------------------------------------------------------------------
// 1. region sums: c-split over 4 blocks (per-c (t,r) chain order unchanged)
__global__ __launch_bounds__(64) void region_kernel(const float* __restrict__ x,
                                                    float* __restrict__ region) {
    int bn = blockIdx.x;          // b*NWIN + n
    int b = bn >> 3, n = bn & 7;
    int c = blockIdx.y * 64 + threadIdx.x;
    float tot = 0.0f;
    for (int r = 0; r < WIN; ++r) {
        int l = n * WIN + r;
        float s = 0.0f;
        for (int t = 0; t < TT; ++t) {
            s += x[(((size_t)t * BB + b) * LL + l) * CC + c];
        }
        tot += s;
    }
    region[(size_t)bn * CC + c] = tot;
}

// ---------------------------------------------------------------------------
// 2. routing
__global__ __launch_bounds__(64) void route_kernel(const float* __restrict__ region,
                                                   int* __restrict__ idx) {
    int b = blockIdx.x;
    __shared__ float reg[NWIN][CC];
    __shared__ float attn_r[NWIN][NWIN];
    int tid = threadIdx.x;
    for (int e = tid; e < NWIN * CC; e += 64)
        reg[e >> 8][e & 255] = region[(size_t)b * NWIN * CC + e];
    __syncthreads();
    int n = tid >> 3, m = tid & 7;
    float s = 0.0f;
    for (int c = 0; c < CC; ++c) s += reg[n][c] * reg[m][c];
    attn_r[n][m] = s * 0.0625f;   // C^-0.5 = 1/16 exact
    __syncthreads();
    if (tid < NWIN) {
        float vals[NWIN];
        for (int m2 = 0; m2 < NWIN; ++m2) vals[m2] = attn_r[tid][m2];
        for (int kk = 0; kk < TOPKN; ++kk) {
            int bi = 0; float bv = vals[0];
            for (int m2 = 1; m2 < NWIN; ++m2) {
                if (vals[m2] > bv) { bv = vals[m2]; bi = m2; }
            }
            idx[(b * NWIN + tid) * TOPKN + kk] = bi;
            vals[bi] = -INFINITY;
        }
    }
}

// ---------------------------------------------------------------------------
// 3a. fp32 GEMM + bias, 128x128 tile (qkv), conflict-free B reads.
__global__ __launch_bounds__(256, 3) void gemm_bias128(const float* __restrict__ A,
                                                       const float* __restrict__ W,
                                                       const float* __restrict__ bias,
                                                       float* __restrict__ C,
                                                       int M, int N, int K) {
    const int BM = 128, BN = 128, BK = 16, TM = 8;
    __shared__ float As[BK][BM + 4];
    __shared__ float Bs[BK][136];
    int tid = threadIdx.x;
    int tx = tid & 15, ty = tid >> 4;
    int bm = blockIdx.x * BM, bn = blockIdx.y * BN;
    float acc[TM][8] = {};
    for (int k0 = 0; k0 < K; k0 += BK) {
#pragma unroll
        for (int it = 0; it < 2; ++it) {
            int i = it * 256 + tid;
            int row = i >> 2, kc = (i & 3) * 4;
            float4 v = *(const float4*)(A + (size_t)(bm + row) * K + k0 + kc);
            As[kc + 0][row] = v.x; As[kc + 1][row] = v.y;
            As[kc + 2][row] = v.z; As[kc + 3][row] = v.w;
        }
#pragma unroll
        for (int it = 0; it < 2; ++it) {
            int i = it * 256 + tid;
            int kr = i >> 5, nc = (i & 31) * 4;
            float4 v = *(const float4*)(W + (size_t)(k0 + kr) * N + bn + nc);
            *(float4*)&Bs[kr][nc] = v;
        }
        __syncthreads();
#pragma unroll
        for (int kk = 0; kk < BK; ++kk) {
            float a[TM], bb[8];
            const float4* ap = (const float4*)&As[kk][ty * TM];
            float4 a0 = ap[0], a1 = ap[1];
            a[0]=a0.x; a[1]=a0.y; a[2]=a0.z; a[3]=a0.w;
            a[4]=a1.x; a[5]=a1.y; a[6]=a1.z; a[7]=a1.w;
            float4 b0 = *(const float4*)&Bs[kk][tx * 4];
            float4 b1 = *(const float4*)&Bs[kk][64 + tx * 4];
            bb[0]=b0.x; bb[1]=b0.y; bb[2]=b0.z; bb[3]=b0.w;
            bb[4]=b1.x; bb[5]=b1.y; bb[6]=b1.z; bb[7]=b1.w;
#pragma unroll
            for (int i = 0; i < TM; ++i)
#pragma unroll
                for (int j = 0; j < 8; ++j)
                    acc[i][j] = fmaf(a[i], bb[j], acc[i][j]);
        }
        __syncthreads();
    }
#pragma unroll
    for (int i = 0; i < TM; ++i) {
        int row = bm + ty * TM + i;
        int col0 = bn + tx * 4;
        int col1 = bn + 64 + tx * 4;
        float4 o0 = make_float4(acc[i][0] + bias[col0 + 0], acc[i][1] + bias[col0 + 1],
                                acc[i][2] + bias[col0 + 2], acc[i][3] + bias[col0 + 3]);
        float4 o1 = make_float4(acc[i][4] + bias[col1 + 0], acc[i][5] + bias[col1 + 1],
                                acc[i][6] + bias[col1 + 2], acc[i][7] + bias[col1 + 3]);
        *(float4*)&C[(size_t)row * N + col0] = o0;
        *(float4*)&C[(size_t)row * N + col1] = o1;
    }
}

// ---------------------------------------------------------------------------
// 3b. fp32 GEMM + bias, 64x64 tile (proj)
__global__ __launch_bounds__(256, 4) void gemm_bias64(const float* __restrict__ A,
                                                      const float* __restrict__ W,
                                                      const float* __restrict__ bias,
                                                      float* __restrict__ C,
                                                      int M, int N, int K) {
    const int BM = 64, BN = 64, BK = 16;
    __shared__ float As[BK][BM + 4];
    __shared__ float Bs[BK][72];
    int tid = threadIdx.x;
    int tx = tid & 15, ty = tid >> 4;
    int bm = blockIdx.x * BM, bn = blockIdx.y * BN;
    float acc[4][4] = {};
    for (int k0 = 0; k0 < K; k0 += BK) {
        {
            int row = tid >> 2, kc = (tid & 3) * 4;
            float4 v = *(const float4*)(A + (size_t)(bm + row) * K + k0 + kc);
            As[kc + 0][row] = v.x; As[kc + 1][row] = v.y;
            As[kc + 2][row] = v.z; As[kc + 3][row] = v.w;
        }
        {
            int kr = tid >> 4, nc = (tid & 15) * 4;
            float4 v = *(const float4*)(W + (size_t)(k0 + kr) * N + bn + nc);
            *(float4*)&Bs[kr][nc] = v;
        }
        __syncthreads();
#pragma unroll
        for (int kk = 0; kk < BK; ++kk) {
            float4 av = *(const float4*)&As[kk][ty * 4];
            float4 bv = *(const float4*)&Bs[kk][tx * 4];
            float a[4] = {av.x, av.y, av.z, av.w};
            float bb[4] = {bv.x, bv.y, bv.z, bv.w};
#pragma unroll
            for (int i = 0; i < 4; ++i)
#pragma unroll
                for (int j = 0; j < 4; ++j)
                    acc[i][j] = fmaf(a[i], bb[j], acc[i][j]);
        }
        __syncthreads();
    }
#pragma unroll
    for (int i = 0; i < 4; ++i) {
        int row = bm + ty * 4 + i;
        int col = bn + tx * 4;
        float4 o = make_float4(acc[i][0] + bias[col + 0], acc[i][1] + bias[col + 1],
                               acc[i][2] + bias[col + 2], acc[i][3] + bias[col + 3]);
        *(float4*)&C[(size_t)row * N + col] = o;
    }
}

// ---------------------------------------------------------------------------
// 4. LIF over T
__global__ __launch_bounds__(256) void lif_kernel(const float* src, float* dst, size_t stride) {
    size_t i = ((size_t)blockIdx.x * blockDim.x + threadIdx.x) * 4;
    float v[4] = {0.f, 0.f, 0.f, 0.f};
    for (int t = 0; t < TT; ++t) {
        float4 xv4 = *(const float4*)(src + (size_t)t * stride + i);
        float xv[4] = {xv4.x, xv4.y, xv4.z, xv4.w};
        float sp[4];
#pragma unroll
        for (int j = 0; j < 4; ++j) {
            v[j] = v[j] + (xv[j] - v[j]) * 0.5f;
            bool fire = (v[j] >= 1.0f);
            sp[j] = fire ? 1.0f : 0.0f;
            v[j] = fire ? 0.0f : v[j];
        }
        *(float4*)(dst + (size_t)t * stride + i) = make_float4(sp[0], sp[1], sp[2], sp[3]);
    }
}

// ---------------------------------------------------------------------------
// 4b. pack Q/K spike bits
__global__ __launch_bounds__(256) void pack_kernel(const float* __restrict__ spk,
                                                   uint32_t* __restrict__ pk) {
    size_t g = (size_t)blockIdx.x * 256 + threadIdx.x;   // over 16384*512
    int row = (int)(g >> 9);
    int col = (int)(g & 511);
    float v = spk[(size_t)row * C3 + col];
    unsigned long long m = __ballot(v >= 0.5f);
    int lane = threadIdx.x & 63;
    if ((lane & 31) == 0)
        pk[(size_t)row * 16 + (col >> 5)] = (lane < 32) ? (uint32_t)m : (uint32_t)(m >> 32);
}

// ---------------------------------------------------------------------------
// 5. fused attention v14. Block = (t,b,n,hp,h): 1024 blocks, 128 threads.
//    16-row "eighth" double-buffer (1 gload_lds/thread per stage). Inner loop
//    NOT unrolled (icache); per eighth: phase 1 gathers 32 P values into regs
//    (independent ds_reads batch), phase 2 streams V with immediate offsets.
//    FP chains identical (ascending k) -> bitwise exact.
__global__ __launch_bounds__(128, 2) void attn_fused(const float* __restrict__ spk,
                                                     const uint32_t* __restrict__ pk,
                                                     const int* __restrict__ idxws,
                                                     float* __restrict__ out) {
    int bid = blockIdx.x;
    int h = bid & 1, hp = (bid >> 1) & 3, n = (bid >> 3) & 7, b = (bid >> 6) & 3, t = bid >> 8;
    __shared__ __align__(16) float Vlds[2][16][32];   // 2 x 2 KB eighth buffers
    __shared__ float ptab[33][WIN];                   // 16.9 KB
    __shared__ __align__(16) uint32_t kbs[4 * WIN];   // 2 KB (this h only)
    int tid = threadIdx.x;                            // 128 threads
    int qg = tid & 63;
    int dh = tid >> 6;
    int lbase = (t * BB + b) * LL;

    const int* ip = idxws + (b * NWIN + n) * TOPKN;
    int s0r = ip[0], s1r = ip[1], s2r = ip[2], s3r = ip[3];

    // stage gathered K bit-words (this h)
#pragma unroll 4
    for (int e = tid; e < 512; e += 128) {
        int w = e >> 7;
        int sw = (w == 0) ? s0r : (w == 1) ? s1r : (w == 2) ? s2r : s3r;
        int row = sw * WIN + (e & 127);
        kbs[e] = pk[(size_t)(lbase + row) * 16 + 8 + hp * 2 + h];
    }
    uint32_t qw0 = pk[(size_t)(lbase + n * WIN + qg) * 16 + hp * 2 + h];
    uint32_t qw1 = pk[(size_t)(lbase + n * WIN + qg + 64) * 16 + hp * 2 + h];
    uint32_t qwt = pk[(size_t)(lbase + n * WIN + tid) * 16 + hp * 2 + h];
    __syncthreads();   // kbs visible

    // V DMA geometry: per-lane global src; LDS dest = wave-uniform base + lane*16
    const float* vsrc = spk + (size_t)lbase * C3 + 512 + hp * 64 + h * 32
                        + (size_t)(tid >> 3) * C3 + (tid & 7) * 4;
    int wvoff = (tid >> 6) * 1024;   // wave-uniform

#define STAGE_E(hw_)                                                                 \
    do {                                                                             \
        int hw = (hw_);                                                              \
        int ww = hw >> 3;                                                            \
        int sw = (ww == 0) ? s0r : (ww == 1) ? s1r : (ww == 2) ? s2r : s3r;          \
        const float* src = vsrc + (size_t)sw * (WIN * C3)                            \
                                + (size_t)(hw & 7) * 16 * C3;                        \
        char* lb = (char*)(&Vlds[hw & 1][0][0]) + wvoff;                             \
        __builtin_amdgcn_global_load_lds(                                            \
            (const __attribute__((address_space(1))) void*)src,                      \
            (__attribute__((address_space(3))) void*)lb, 16, 0, 0);                  \
    } while (0)

    STAGE_E(0);
    STAGE_E(1);

    // ---- fused softmax stats for q = tid (hidden under in-flight DMA)
    const float ALPHA_SC = 0.17677669529663687f;   // hd^-0.5
    const uint4* kb4 = (const uint4*)kbs;
    int smax = 0;
#pragma unroll 8
    for (int k4 = 0; k4 < 128; ++k4) {
        uint4 w4 = kb4[k4];
        smax = max(smax, __popc(qwt & w4.x));
        smax = max(smax, __popc(qwt & w4.y));
        smax = max(smax, __popc(qwt & w4.z));
        smax = max(smax, __popc(qwt & w4.w));
    }
    float am = __fmul_rn((float)smax, ALPHA_SC);
    float Z = 0.0f;
#pragma unroll 4
    for (int k4 = 0; k4 < 128; ++k4) {
        uint4 w4 = kb4[k4];
        Z += expf(__fsub_rn(__fmul_rn((float)__popc(qwt & w4.x), ALPHA_SC), am));
        Z += expf(__fsub_rn(__fmul_rn((float)__popc(qwt & w4.y), ALPHA_SC), am));
        Z += expf(__fsub_rn(__fmul_rn((float)__popc(qwt & w4.z), ALPHA_SC), am));
        Z += expf(__fsub_rn(__fmul_rn((float)__popc(qwt & w4.w), ALPHA_SC), am));
    }
    for (int s = 0; s <= 32; ++s)
        ptab[s][tid] = expf(__fsub_rn(__fmul_rn((float)s, ALPHA_SC), am)) / Z;

    float acc0[16], acc1[16];
#pragma unroll
    for (int d = 0; d < 16; ++d) { acc0[d] = 0.0f; acc1[d] = 0.0f; }

    asm volatile("s_waitcnt vmcnt(1)" ::: "memory");   // eighth 0 done; 1 in flight
    __syncthreads();                                   // Vlds[0] + ptab visible

#pragma unroll 1
    for (int hw = 0; hw < 32; ++hw) {
        const uint4* kw4 = kb4 + hw * 4;
        const float* vb = &Vlds[hw & 1][0][dh * 16];

        // phase 1: gather all 32 P values (independent ds_reads, batchable)
        float Pv0[16], Pv1[16];
#pragma unroll
        for (int g = 0; g < 4; ++g) {
            uint4 kw = kw4[g];
            Pv0[g*4+0] = ptab[__popc(qw0 & kw.x)][qg];
            Pv1[g*4+0] = ptab[__popc(qw1 & kw.x)][qg + 64];
            Pv0[g*4+1] = ptab[__popc(qw0 & kw.y)][qg];
            Pv1[g*4+1] = ptab[__popc(qw1 & kw.y)][qg + 64];
            Pv0[g*4+2] = ptab[__popc(qw0 & kw.z)][qg];
            Pv1[g*4+2] = ptab[__popc(qw1 & kw.z)][qg + 64];
            Pv0[g*4+3] = ptab[__popc(qw0 & kw.w)][qg];
            Pv1[g*4+3] = ptab[__popc(qw1 & kw.w)][qg + 64];
        }

        // phase 2: FMA sweep, V reads at immediate offsets (ascending k)
#pragma unroll
        for (int r = 0; r < 16; ++r) {
            const float4* vp = (const float4*)(vb + r * 32);
            float4 v0 = vp[0], v1 = vp[1], v2 = vp[2], v3 = vp[3];
            float P0 = Pv0[r], P1 = Pv1[r];
            acc0[ 0] = fmaf(P0, v0.x, acc0[ 0]);  acc1[ 0] = fmaf(P1, v0.x, acc1[ 0]);
            acc0[ 1] = fmaf(P0, v0.y, acc0[ 1]);  acc1[ 1] = fmaf(P1, v0.y, acc1[ 1]);
            acc0[ 2] = fmaf(P0, v0.z, acc0[ 2]);  acc1[ 2] = fmaf(P1, v0.z, acc1[ 2]);
            acc0[ 3] = fmaf(P0, v0.w, acc0[ 3]);  acc1[ 3] = fmaf(P1, v0.w, acc1[ 3]);
            acc0[ 4] = fmaf(P0, v1.x, acc0[ 4]);  acc1[ 4] = fmaf(P1, v1.x, acc1[ 4]);
            acc0[ 5] = fmaf(P0, v1.y, acc0[ 5]);  acc1[ 5] = fmaf(P1, v1.y, acc1[ 5]);
            acc0[ 6] = fmaf(P0, v1.z, acc0[ 6]);  acc1[ 6] = fmaf(P1, v1.z, acc1[ 6]);
            acc0[ 7] = fmaf(P0, v1.w, acc0[ 7]);  acc1[ 7] = fmaf(P1, v1.w, acc1[ 7]);
            acc0[ 8] = fmaf(P0, v2.x, acc0[ 8]);  acc1[ 8] = fmaf(P1, v2.x, acc1[ 8]);
            acc0[ 9] = fmaf(P0, v2.y, acc0[ 9]);  acc1[ 9] = fmaf(P1, v2.y, acc1[ 9]);
            acc0[10] = fmaf(P0, v2.z, acc0[10]);  acc1[10] = fmaf(P1, v2.z, acc1[10]);
            acc0[11] = fmaf(P0, v2.w, acc0[11]);  acc1[11] = fmaf(P1, v2.w, acc1[11]);
            acc0[12] = fmaf(P0, v3.x, acc0[12]);  acc1[12] = fmaf(P1, v3.x, acc1[12]);
            acc0[13] = fmaf(P0, v3.y, acc0[13]);  acc1[13] = fmaf(P1, v3.y, acc1[13]);
            acc0[14] = fmaf(P0, v3.z, acc0[14]);  acc1[14] = fmaf(P1, v3.z, acc1[14]);
            acc0[15] = fmaf(P0, v3.w, acc0[15]);  acc1[15] = fmaf(P1, v3.w, acc1[15]);
        }

        if (hw < 31) {
            __syncthreads();              // all waves done reading buf[hw&1]
            if (hw < 30) {
                STAGE_E(hw + 2);          // refill buf[hw&1]
                asm volatile("s_waitcnt vmcnt(1)" ::: "memory");  // drain S(hw+1)
            } else {
                asm volatile("s_waitcnt vmcnt(0)" ::: "memory");  // drain S(31)
            }
            __syncthreads();              // eighth hw+1 visible
        }
    }
#undef STAGE_E

    size_t ob0 = (size_t)(lbase + n * WIN + qg) * CC + (hp * 2 + h) * 32 + dh * 16;
    size_t ob1 = ob0 + (size_t)64 * CC;
#pragma unroll
    for (int d = 0; d < 16; ++d) out[ob0 + d] = acc0[d];
#pragma unroll
    for (int d = 0; d < 16; ++d) out[ob1 + d] = acc1[d];
}

// ---------------------------------------------------------------------------
extern "C" void kernel_launch(void* const* d_in, const int* in_sizes, int n_in,
                              void* d_out, int out_size, void* d_ws, size_t ws_size,
                              hipStream_t stream) {
    const float* x      = (const float*)d_in[0];
    const float* w_qkv  = (const float*)d_in[1];
    const float* b_qkv  = (const float*)d_in[2];
    const float* w_proj = (const float*)d_in[3];
    const float* b_proj = (const float*)d_in[4];
    float* ws = (float*)d_ws;

    float* qkv      = ws;                 // 12582912 floats [T,B,L,3C] (spikes after LIF)
    float* attn_out = ws + 12582912;      // 4194304 floats [T,B,L,C]
    float* proj     = ws + 16777216;      // 4194304 floats [T,B,L,C]
    uint32_t* pkb   = (uint32_t*)proj;    // 262144 u32: aliases proj (dead before gemm_proj)
    float* region   = ws + 20971520;      // 8192 floats
    int*   idxp     = (int*)(ws + 20979712);  // 128 ints
    float* outp     = (float*)d_out;

    region_kernel<<<dim3(BB * NWIN, 4), dim3(64), 0, stream>>>(x, region);
    route_kernel<<<dim3(BB), dim3(64), 0, stream>>>(region, idxp);
    gemm_bias128<<<dim3(128, 6), dim3(256), 0, stream>>>(x, w_qkv, b_qkv, qkv,
                                                         TT * BB * LL, C3, CC);
    lif_kernel<<<dim3(3072), dim3(256), 0, stream>>>(qkv, qkv, (size_t)BB * LL * C3);
    pack_kernel<<<dim3(32768), dim3(256), 0, stream>>>(qkv, pkb);
    attn_fused<<<dim3(TT * BB * NWIN * 4 * 2), dim3(128), 0, stream>>>(qkv, pkb, idxp, attn_out);
    gemm_bias64<<<dim3(256, 4), dim3(256), 0, stream>>>(attn_out, w_proj, b_proj, proj,
                                                        TT * BB * LL, CC, CC);
    lif_kernel<<<dim3(1024), dim3(256), 0, stream>>>(proj, outp, (size_t)BB * LL * CC);
}

// Round 15
// 280.861 us; speedup vs baseline: 2.0517x; 2.0517x over previous
//
#include <hip/hip_runtime.h>
#include <cstdint>
#include <cstddef>

#define TT 4
#define BB 4
#define LL 1024
#define CC 256
#define HH 8
#define HD 32
#define NWIN 8
#define WIN 128
#define TOPKN 4
#define C3 768

// ---------------------------------------------------------------------------
// 1. region sums: c-split over 4 blocks (per-c (t,r) chain order unchanged)
__global__ __launch_bounds__(64) void region_kernel(const float* __restrict__ x,
                                                    float* __restrict__ region) {
    int bn = blockIdx.x;          // b*NWIN + n
    int b = bn >> 3, n = bn & 7;
    int c = blockIdx.y * 64 + threadIdx.x;
    float tot = 0.0f;
    for (int r = 0; r < WIN; ++r) {
        int l = n * WIN + r;
        float s = 0.0f;
        for (int t = 0; t < TT; ++t) {
            s += x[(((size_t)t * BB + b) * LL + l) * CC + c];
        }
        tot += s;
    }
    region[(size_t)bn * CC + c] = tot;
}

// ---------------------------------------------------------------------------
// 2. routing
__global__ __launch_bounds__(64) void route_kernel(const float* __restrict__ region,
                                                   int* __restrict__ idx) {
    int b = blockIdx.x;
    __shared__ float reg[NWIN][CC];
    __shared__ float attn_r[NWIN][NWIN];
    int tid = threadIdx.x;
    for (int e = tid; e < NWIN * CC; e += 64)
        reg[e >> 8][e & 255] = region[(size_t)b * NWIN * CC + e];
    __syncthreads();
    int n = tid >> 3, m = tid & 7;
    float s = 0.0f;
    for (int c = 0; c < CC; ++c) s += reg[n][c] * reg[m][c];
    attn_r[n][m] = s * 0.0625f;   // C^-0.5 = 1/16 exact
    __syncthreads();
    if (tid < NWIN) {
        float vals[NWIN];
        for (int m2 = 0; m2 < NWIN; ++m2) vals[m2] = attn_r[tid][m2];
        for (int kk = 0; kk < TOPKN; ++kk) {
            int bi = 0; float bv = vals[0];
            for (int m2 = 1; m2 < NWIN; ++m2) {
                if (vals[m2] > bv) { bv = vals[m2]; bi = m2; }
            }
            idx[(b * NWIN + tid) * TOPKN + kk] = bi;
            vals[bi] = -INFINITY;
        }
    }
}

// ---------------------------------------------------------------------------
// 3a. fp32 GEMM + bias, 128x128 tile (qkv), conflict-free B reads.
__global__ __launch_bounds__(256, 3) void gemm_bias128(const float* __restrict__ A,
                                                       const float* __restrict__ W,
                                                       const float* __restrict__ bias,
                                                       float* __restrict__ C,
                                                       int M, int N, int K) {
    const int BM = 128, BN = 128, BK = 16, TM = 8;
    __shared__ float As[BK][BM + 4];
    __shared__ float Bs[BK][136];
    int tid = threadIdx.x;
    int tx = tid & 15, ty = tid >> 4;
    int bm = blockIdx.x * BM, bn = blockIdx.y * BN;
    float acc[TM][8] = {};
    for (int k0 = 0; k0 < K; k0 += BK) {
#pragma unroll
        for (int it = 0; it < 2; ++it) {
            int i = it * 256 + tid;
            int row = i >> 2, kc = (i & 3) * 4;
            float4 v = *(const float4*)(A + (size_t)(bm + row) * K + k0 + kc);
            As[kc + 0][row] = v.x; As[kc + 1][row] = v.y;
            As[kc + 2][row] = v.z; As[kc + 3][row] = v.w;
        }
#pragma unroll
        for (int it = 0; it < 2; ++it) {
            int i = it * 256 + tid;
            int kr = i >> 5, nc = (i & 31) * 4;
            float4 v = *(const float4*)(W + (size_t)(k0 + kr) * N + bn + nc);
            *(float4*)&Bs[kr][nc] = v;
        }
        __syncthreads();
#pragma unroll
        for (int kk = 0; kk < BK; ++kk) {
            float a[TM], bb[8];
            const float4* ap = (const float4*)&As[kk][ty * TM];
            float4 a0 = ap[0], a1 = ap[1];
            a[0]=a0.x; a[1]=a0.y; a[2]=a0.z; a[3]=a0.w;
            a[4]=a1.x; a[5]=a1.y; a[6]=a1.z; a[7]=a1.w;
            float4 b0 = *(const float4*)&Bs[kk][tx * 4];
            float4 b1 = *(const float4*)&Bs[kk][64 + tx * 4];
            bb[0]=b0.x; bb[1]=b0.y; bb[2]=b0.z; bb[3]=b0.w;
            bb[4]=b1.x; bb[5]=b1.y; bb[6]=b1.z; bb[7]=b1.w;
#pragma unroll
            for (int i = 0; i < TM; ++i)
#pragma unroll
                for (int j = 0; j < 8; ++j)
                    acc[i][j] = fmaf(a[i], bb[j], acc[i][j]);
        }
        __syncthreads();
    }
#pragma unroll
    for (int i = 0; i < TM; ++i) {
        int row = bm + ty * TM + i;
        int col0 = bn + tx * 4;
        int col1 = bn + 64 + tx * 4;
        float4 o0 = make_float4(acc[i][0] + bias[col0 + 0], acc[i][1] + bias[col0 + 1],
                                acc[i][2] + bias[col0 + 2], acc[i][3] + bias[col0 + 3]);
        float4 o1 = make_float4(acc[i][4] + bias[col1 + 0], acc[i][5] + bias[col1 + 1],
                                acc[i][6] + bias[col1 + 2], acc[i][7] + bias[col1 + 3]);
        *(float4*)&C[(size_t)row * N + col0] = o0;
        *(float4*)&C[(size_t)row * N + col1] = o1;
    }
}

// ---------------------------------------------------------------------------
// 3b. fp32 GEMM + bias, 64x64 tile (proj)
__global__ __launch_bounds__(256, 4) void gemm_bias64(const float* __restrict__ A,
                                                      const float* __restrict__ W,
                                                      const float* __restrict__ bias,
                                                      float* __restrict__ C,
                                                      int M, int N, int K) {
    const int BM = 64, BN = 64, BK = 16;
    __shared__ float As[BK][BM + 4];
    __shared__ float Bs[BK][72];
    int tid = threadIdx.x;
    int tx = tid & 15, ty = tid >> 4;
    int bm = blockIdx.x * BM, bn = blockIdx.y * BN;
    float acc[4][4] = {};
    for (int k0 = 0; k0 < K; k0 += BK) {
        {
            int row = tid >> 2, kc = (tid & 3) * 4;
            float4 v = *(const float4*)(A + (size_t)(bm + row) * K + k0 + kc);
            As[kc + 0][row] = v.x; As[kc + 1][row] = v.y;
            As[kc + 2][row] = v.z; As[kc + 3][row] = v.w;
        }
        {
            int kr = tid >> 4, nc = (tid & 15) * 4;
            float4 v = *(const float4*)(W + (size_t)(k0 + kr) * N + bn + nc);
            *(float4*)&Bs[kr][nc] = v;
        }
        __syncthreads();
#pragma unroll
        for (int kk = 0; kk < BK; ++kk) {
            float4 av = *(const float4*)&As[kk][ty * 4];
            float4 bv = *(const float4*)&Bs[kk][tx * 4];
            float a[4] = {av.x, av.y, av.z, av.w};
            float bb[4] = {bv.x, bv.y, bv.z, bv.w};
#pragma unroll
            for (int i = 0; i < 4; ++i)
#pragma unroll
                for (int j = 0; j < 4; ++j)
                    acc[i][j] = fmaf(a[i], bb[j], acc[i][j]);
        }
        __syncthreads();
    }
#pragma unroll
    for (int i = 0; i < 4; ++i) {
        int row = bm + ty * 4 + i;
        int col = bn + tx * 4;
        float4 o = make_float4(acc[i][0] + bias[col + 0], acc[i][1] + bias[col + 1],
                               acc[i][2] + bias[col + 2], acc[i][3] + bias[col + 3]);
        *(float4*)&C[(size_t)row * N + col] = o;
    }
}

// ---------------------------------------------------------------------------
// 4. LIF over T
__global__ __launch_bounds__(256) void lif_kernel(const float* src, float* dst, size_t stride) {
    size_t i = ((size_t)blockIdx.x * blockDim.x + threadIdx.x) * 4;
    float v[4] = {0.f, 0.f, 0.f, 0.f};
    for (int t = 0; t < TT; ++t) {
        float4 xv4 = *(const float4*)(src + (size_t)t * stride + i);
        float xv[4] = {xv4.x, xv4.y, xv4.z, xv4.w};
        float sp[4];
#pragma unroll
        for (int j = 0; j < 4; ++j) {
            v[j] = v[j] + (xv[j] - v[j]) * 0.5f;
            bool fire = (v[j] >= 1.0f);
            sp[j] = fire ? 1.0f : 0.0f;
            v[j] = fire ? 0.0f : v[j];
        }
        *(float4*)(dst + (size_t)t * stride + i) = make_float4(sp[0], sp[1], sp[2], sp[3]);
    }
}

// ---------------------------------------------------------------------------
// 4b. pack Q/K spike bits
__global__ __launch_bounds__(256) void pack_kernel(const float* __restrict__ spk,
                                                   uint32_t* __restrict__ pk) {
    size_t g = (size_t)blockIdx.x * 256 + threadIdx.x;   // over 16384*512
    int row = (int)(g >> 9);
    int col = (int)(g & 511);
    float v = spk[(size_t)row * C3 + col];
    unsigned long long m = __ballot(v >= 0.5f);
    int lane = threadIdx.x & 63;
    if ((lane & 31) == 0)
        pk[(size_t)row * 16 + (col >> 5)] = (lane < 32) ? (uint32_t)m : (uint32_t)(m >> 32);
}

// ---------------------------------------------------------------------------
// 5. fused attention v15 = r13 structure with 256 threads, 1 q/thread.
//    Block = (t,b,n,hp,h): 1024 blocks, 256 threads = (q 0..127, dh 0..1)
//    -> 4 waves/SIMD (2x r13). V via global_load_lds DMA, 64-row halves
//    double-buffered, counted vmcnt(2). sm stats on threads 0..127 (q==tid),
//    identical expression sequence. FP chains ascending k -> bitwise exact.
__global__ __launch_bounds__(256, 4) void attn_fused(const float* __restrict__ spk,
                                                     const uint32_t* __restrict__ pk,
                                                     const int* __restrict__ idxws,
                                                     float* __restrict__ out) {
    int bid = blockIdx.x;
    int h = bid & 1, hp = (bid >> 1) & 3, n = (bid >> 3) & 7, b = (bid >> 6) & 3, t = bid >> 8;
    __shared__ __align__(16) float Vlds[2][64][32];   // 2 x 8 KB half-window buffers
    __shared__ float ptab[33][WIN];                   // 16.9 KB
    __shared__ __align__(16) uint32_t kbs[4 * WIN];   // 2 KB (this h only)
    int tid = threadIdx.x;                            // 256 threads
    int q = tid & 127, dh = tid >> 7;
    int lbase = (t * BB + b) * LL;

    const int* ip = idxws + (b * NWIN + n) * TOPKN;
    int s0r = ip[0], s1r = ip[1], s2r = ip[2], s3r = ip[3];

    // stage gathered K bit-words (this h): 512 words, 2 per thread
#pragma unroll 2
    for (int e = tid; e < 512; e += 256) {
        int w = e >> 7;
        int sw = (w == 0) ? s0r : (w == 1) ? s1r : (w == 2) ? s2r : s3r;
        int row = sw * WIN + (e & 127);
        kbs[e] = pk[(size_t)(lbase + row) * 16 + 8 + hp * 2 + h];
    }
    uint32_t qw = pk[(size_t)(lbase + n * WIN + q) * 16 + hp * 2 + h];
    __syncthreads();   // kbs visible

    // V DMA geometry: per-lane global src; LDS dest = wave-uniform base + lane*16.
    // Thread tid covers rows {tid>>3, 32+(tid>>3)} cols (tid&7)*4 of each half.
    const float* vsrc = spk + (size_t)lbase * C3 + 512 + hp * 64 + h * 32
                        + (size_t)(tid >> 3) * C3 + (tid & 7) * 4;
    int wvoff = (tid >> 6) * 1024;   // wave-uniform (wave id * 1 KB)

#define STAGE_HALF(hw_)                                                              \
    do {                                                                             \
        int hw = (hw_);                                                              \
        int ww = hw >> 1;                                                            \
        int sw = (ww == 0) ? s0r : (ww == 1) ? s1r : (ww == 2) ? s2r : s3r;          \
        const float* src = vsrc + (size_t)sw * (WIN * C3)                            \
                                + (size_t)(hw & 1) * 64 * C3;                        \
        char* lb = (char*)(&Vlds[hw & 1][0][0]) + wvoff;                             \
        __builtin_amdgcn_global_load_lds(                                            \
            (const __attribute__((address_space(1))) void*)src,                      \
            (__attribute__((address_space(3))) void*)lb, 16, 0, 0);                  \
        __builtin_amdgcn_global_load_lds(                                            \
            (const __attribute__((address_space(1))) void*)(src + 32 * C3),          \
            (__attribute__((address_space(3))) void*)(lb + 4096), 16, 0, 0);         \
    } while (0)

    STAGE_HALF(0);
    STAGE_HALF(1);

    // ---- fused softmax stats for q = tid (threads 0..127; hidden under DMA)
    const float ALPHA_SC = 0.17677669529663687f;   // hd^-0.5
    const uint4* kb4 = (const uint4*)kbs;
    if (tid < 128) {
        int smax = 0;
#pragma unroll 8
        for (int k4 = 0; k4 < 128; ++k4) {
            uint4 w4 = kb4[k4];
            smax = max(smax, __popc(qw & w4.x));
            smax = max(smax, __popc(qw & w4.y));
            smax = max(smax, __popc(qw & w4.z));
            smax = max(smax, __popc(qw & w4.w));
        }
        float am = __fmul_rn((float)smax, ALPHA_SC);
        float Z = 0.0f;
#pragma unroll 4
        for (int k4 = 0; k4 < 128; ++k4) {
            uint4 w4 = kb4[k4];
            Z += expf(__fsub_rn(__fmul_rn((float)__popc(qw & w4.x), ALPHA_SC), am));
            Z += expf(__fsub_rn(__fmul_rn((float)__popc(qw & w4.y), ALPHA_SC), am));
            Z += expf(__fsub_rn(__fmul_rn((float)__popc(qw & w4.z), ALPHA_SC), am));
            Z += expf(__fsub_rn(__fmul_rn((float)__popc(qw & w4.w), ALPHA_SC), am));
        }
        for (int s = 0; s <= 32; ++s)
            ptab[s][tid] = expf(__fsub_rn(__fmul_rn((float)s, ALPHA_SC), am)) / Z;
    }

    float acc[16];
#pragma unroll
    for (int d = 0; d < 16; ++d) acc[d] = 0.0f;

    asm volatile("s_waitcnt vmcnt(2)" ::: "memory");   // half0 done; half1 in flight
    __syncthreads();                                   // half0 + ptab visible

#pragma unroll
    for (int hw = 0; hw < 8; ++hw) {
        // compute half hw: 16 groups of 4 rows, 2-row batches, ascending k
        const uint4* kw4 = kb4 + hw * 16;
        const float* vb = &Vlds[hw & 1][0][dh * 16];
#pragma unroll 2
        for (int g = 0; g < 16; ++g) {
            uint4 kw = kw4[g];
            const float* pr = vb + g * 128;
#pragma unroll
            for (int jp = 0; jp < 2; ++jp) {
                uint32_t ka = (jp == 0) ? kw.x : kw.z;
                uint32_t kb_ = (jp == 0) ? kw.y : kw.w;
                float Pa = ptab[__popc(qw & ka)][q];
                float Pb = ptab[__popc(qw & kb_)][q];
                const float4* va = (const float4*)(pr + jp * 64);
                const float4* vbp = (const float4*)(pr + jp * 64 + 32);
                float4 a0 = va[0], a1 = va[1], a2 = va[2], a3 = va[3];
                float4 b0 = vbp[0], b1 = vbp[1], b2 = vbp[2], b3 = vbp[3];
                // row a (k even) then row b (k odd): per-chain ascending k
                acc[ 0] = fmaf(Pa, a0.x, acc[ 0]);
                acc[ 1] = fmaf(Pa, a0.y, acc[ 1]);
                acc[ 2] = fmaf(Pa, a0.z, acc[ 2]);
                acc[ 3] = fmaf(Pa, a0.w, acc[ 3]);
                acc[ 4] = fmaf(Pa, a1.x, acc[ 4]);
                acc[ 5] = fmaf(Pa, a1.y, acc[ 5]);
                acc[ 6] = fmaf(Pa, a1.z, acc[ 6]);
                acc[ 7] = fmaf(Pa, a1.w, acc[ 7]);
                acc[ 8] = fmaf(Pa, a2.x, acc[ 8]);
                acc[ 9] = fmaf(Pa, a2.y, acc[ 9]);
                acc[10] = fmaf(Pa, a2.z, acc[10]);
                acc[11] = fmaf(Pa, a2.w, acc[11]);
                acc[12] = fmaf(Pa, a3.x, acc[12]);
                acc[13] = fmaf(Pa, a3.y, acc[13]);
                acc[14] = fmaf(Pa, a3.z, acc[14]);
                acc[15] = fmaf(Pa, a3.w, acc[15]);
                acc[ 0] = fmaf(Pb, b0.x, acc[ 0]);
                acc[ 1] = fmaf(Pb, b0.y, acc[ 1]);
                acc[ 2] = fmaf(Pb, b0.z, acc[ 2]);
                acc[ 3] = fmaf(Pb, b0.w, acc[ 3]);
                acc[ 4] = fmaf(Pb, b1.x, acc[ 4]);
                acc[ 5] = fmaf(Pb, b1.y, acc[ 5]);
                acc[ 6] = fmaf(Pb, b1.z, acc[ 6]);
                acc[ 7] = fmaf(Pb, b1.w, acc[ 7]);
                acc[ 8] = fmaf(Pb, b2.x, acc[ 8]);
                acc[ 9] = fmaf(Pb, b2.y, acc[ 9]);
                acc[10] = fmaf(Pb, b2.z, acc[10]);
                acc[11] = fmaf(Pb, b2.w, acc[11]);
                acc[12] = fmaf(Pb, b3.x, acc[12]);
                acc[13] = fmaf(Pb, b3.y, acc[13]);
                acc[14] = fmaf(Pb, b3.z, acc[14]);
                acc[15] = fmaf(Pb, b3.w, acc[15]);
            }
        }

        if (hw < 7) {
            __syncthreads();              // all waves done reading buf[hw&1]
            if (hw < 6) {
                STAGE_HALF(hw + 2);       // refill buf[hw&1]
                asm volatile("s_waitcnt vmcnt(2)" ::: "memory");  // drain S(hw+1)
            } else {
                asm volatile("s_waitcnt vmcnt(0)" ::: "memory");  // drain S(7)
            }
            __syncthreads();              // half hw+1 visible to all waves
        }
    }
#undef STAGE_HALF

    size_t ob = (size_t)(lbase + n * WIN + q) * CC + (hp * 2 + h) * 32 + dh * 16;
#pragma unroll
    for (int d = 0; d < 16; ++d) out[ob + d] = acc[d];
}

// ---------------------------------------------------------------------------
extern "C" void kernel_launch(void* const* d_in, const int* in_sizes, int n_in,
                              void* d_out, int out_size, void* d_ws, size_t ws_size,
                              hipStream_t stream) {
    const float* x      = (const float*)d_in[0];
    const float* w_qkv  = (const float*)d_in[1];
    const float* b_qkv  = (const float*)d_in[2];
    const float* w_proj = (const float*)d_in[3];
    const float* b_proj = (const float*)d_in[4];
    float* ws = (float*)d_ws;

    float* qkv      = ws;                 // 12582912 floats [T,B,L,3C] (spikes after LIF)
    float* attn_out = ws + 12582912;      // 4194304 floats [T,B,L,C]
    float* proj     = ws + 16777216;      // 4194304 floats [T,B,L,C]
    uint32_t* pkb   = (uint32_t*)proj;    // 262144 u32: aliases proj (dead before gemm_proj)
    float* region   = ws + 20971520;      // 8192 floats
    int*   idxp     = (int*)(ws + 20979712);  // 128 ints
    float* outp     = (float*)d_out;

    region_kernel<<<dim3(BB * NWIN, 4), dim3(64), 0, stream>>>(x, region);
    route_kernel<<<dim3(BB), dim3(64), 0, stream>>>(region, idxp);
    gemm_bias128<<<dim3(128, 6), dim3(256), 0, stream>>>(x, w_qkv, b_qkv, qkv,
                                                         TT * BB * LL, C3, CC);
    lif_kernel<<<dim3(3072), dim3(256), 0, stream>>>(qkv, qkv, (size_t)BB * LL * C3);
    pack_kernel<<<dim3(32768), dim3(256), 0, stream>>>(qkv, pkb);
    attn_fused<<<dim3(TT * BB * NWIN * 4 * 2), dim3(256), 0, stream>>>(qkv, pkb, idxp, attn_out);
    gemm_bias64<<<dim3(256, 4), dim3(256), 0, stream>>>(attn_out, w_proj, b_proj, proj,
                                                        TT * BB * LL, CC, CC);
    lif_kernel<<<dim3(1024), dim3(256), 0, stream>>>(proj, outp, (size_t)BB * LL * CC);
}

// Round 16
// 261.367 us; speedup vs baseline: 2.2047x; 1.0746x over previous
//
#include <hip/hip_runtime.h>
#include <cstdint>
#include <cstddef>

#define TT 4
#define BB 4
#define LL 1024
#define CC 256
#define HH 8
#define HD 32
#define NWIN 8
#define WIN 128
#define TOPKN 4
#define C3 768

// ---------------------------------------------------------------------------
// 1. region sums: c-split over 4 blocks (per-c (t,r) chain order unchanged)
__global__ __launch_bounds__(64) void region_kernel(const float* __restrict__ x,
                                                    float* __restrict__ region) {
    int bn = blockIdx.x;          // b*NWIN + n
    int b = bn >> 3, n = bn & 7;
    int c = blockIdx.y * 64 + threadIdx.x;
    float tot = 0.0f;
    for (int r = 0; r < WIN; ++r) {
        int l = n * WIN + r;
        float s = 0.0f;
        for (int t = 0; t < TT; ++t) {
            s += x[(((size_t)t * BB + b) * LL + l) * CC + c];
        }
        tot += s;
    }
    region[(size_t)bn * CC + c] = tot;
}

// ---------------------------------------------------------------------------
// 2. routing
__global__ __launch_bounds__(64) void route_kernel(const float* __restrict__ region,
                                                   int* __restrict__ idx) {
    int b = blockIdx.x;
    __shared__ float reg[NWIN][CC];
    __shared__ float attn_r[NWIN][NWIN];
    int tid = threadIdx.x;
    for (int e = tid; e < NWIN * CC; e += 64)
        reg[e >> 8][e & 255] = region[(size_t)b * NWIN * CC + e];
    __syncthreads();
    int n = tid >> 3, m = tid & 7;
    float s = 0.0f;
    for (int c = 0; c < CC; ++c) s += reg[n][c] * reg[m][c];
    attn_r[n][m] = s * 0.0625f;   // C^-0.5 = 1/16 exact
    __syncthreads();
    if (tid < NWIN) {
        float vals[NWIN];
        for (int m2 = 0; m2 < NWIN; ++m2) vals[m2] = attn_r[tid][m2];
        for (int kk = 0; kk < TOPKN; ++kk) {
            int bi = 0; float bv = vals[0];
            for (int m2 = 1; m2 < NWIN; ++m2) {
                if (vals[m2] > bv) { bv = vals[m2]; bi = m2; }
            }
            idx[(b * NWIN + tid) * TOPKN + kk] = bi;
            vals[bi] = -INFINITY;
        }
    }
}

// ---------------------------------------------------------------------------
// 3a. fp32 GEMM + bias, 128x128 tile (qkv), conflict-free B reads.
__global__ __launch_bounds__(256, 3) void gemm_bias128(const float* __restrict__ A,
                                                       const float* __restrict__ W,
                                                       const float* __restrict__ bias,
                                                       float* __restrict__ C,
                                                       int M, int N, int K) {
    const int BM = 128, BN = 128, BK = 16, TM = 8;
    __shared__ float As[BK][BM + 4];
    __shared__ float Bs[BK][136];
    int tid = threadIdx.x;
    int tx = tid & 15, ty = tid >> 4;
    int bm = blockIdx.x * BM, bn = blockIdx.y * BN;
    float acc[TM][8] = {};
    for (int k0 = 0; k0 < K; k0 += BK) {
#pragma unroll
        for (int it = 0; it < 2; ++it) {
            int i = it * 256 + tid;
            int row = i >> 2, kc = (i & 3) * 4;
            float4 v = *(const float4*)(A + (size_t)(bm + row) * K + k0 + kc);
            As[kc + 0][row] = v.x; As[kc + 1][row] = v.y;
            As[kc + 2][row] = v.z; As[kc + 3][row] = v.w;
        }
#pragma unroll
        for (int it = 0; it < 2; ++it) {
            int i = it * 256 + tid;
            int kr = i >> 5, nc = (i & 31) * 4;
            float4 v = *(const float4*)(W + (size_t)(k0 + kr) * N + bn + nc);
            *(float4*)&Bs[kr][nc] = v;
        }
        __syncthreads();
#pragma unroll
        for (int kk = 0; kk < BK; ++kk) {
            float a[TM], bb[8];
            const float4* ap = (const float4*)&As[kk][ty * TM];
            float4 a0 = ap[0], a1 = ap[1];
            a[0]=a0.x; a[1]=a0.y; a[2]=a0.z; a[3]=a0.w;
            a[4]=a1.x; a[5]=a1.y; a[6]=a1.z; a[7]=a1.w;
            float4 b0 = *(const float4*)&Bs[kk][tx * 4];
            float4 b1 = *(const float4*)&Bs[kk][64 + tx * 4];
            bb[0]=b0.x; bb[1]=b0.y; bb[2]=b0.z; bb[3]=b0.w;
            bb[4]=b1.x; bb[5]=b1.y; bb[6]=b1.z; bb[7]=b1.w;
#pragma unroll
            for (int i = 0; i < TM; ++i)
#pragma unroll
                for (int j = 0; j < 8; ++j)
                    acc[i][j] = fmaf(a[i], bb[j], acc[i][j]);
        }
        __syncthreads();
    }
#pragma unroll
    for (int i = 0; i < TM; ++i) {
        int row = bm + ty * TM + i;
        int col0 = bn + tx * 4;
        int col1 = bn + 64 + tx * 4;
        float4 o0 = make_float4(acc[i][0] + bias[col0 + 0], acc[i][1] + bias[col0 + 1],
                                acc[i][2] + bias[col0 + 2], acc[i][3] + bias[col0 + 3]);
        float4 o1 = make_float4(acc[i][4] + bias[col1 + 0], acc[i][5] + bias[col1 + 1],
                                acc[i][6] + bias[col1 + 2], acc[i][7] + bias[col1 + 3]);
        *(float4*)&C[(size_t)row * N + col0] = o0;
        *(float4*)&C[(size_t)row * N + col1] = o1;
    }
}

// ---------------------------------------------------------------------------
// 3b. fp32 GEMM + bias, 64x64 tile (proj)
__global__ __launch_bounds__(256, 4) void gemm_bias64(const float* __restrict__ A,
                                                      const float* __restrict__ W,
                                                      const float* __restrict__ bias,
                                                      float* __restrict__ C,
                                                      int M, int N, int K) {
    const int BM = 64, BN = 64, BK = 16;
    __shared__ float As[BK][BM + 4];
    __shared__ float Bs[BK][72];
    int tid = threadIdx.x;
    int tx = tid & 15, ty = tid >> 4;
    int bm = blockIdx.x * BM, bn = blockIdx.y * BN;
    float acc[4][4] = {};
    for (int k0 = 0; k0 < K; k0 += BK) {
        {
            int row = tid >> 2, kc = (tid & 3) * 4;
            float4 v = *(const float4*)(A + (size_t)(bm + row) * K + k0 + kc);
            As[kc + 0][row] = v.x; As[kc + 1][row] = v.y;
            As[kc + 2][row] = v.z; As[kc + 3][row] = v.w;
        }
        {
            int kr = tid >> 4, nc = (tid & 15) * 4;
            float4 v = *(const float4*)(W + (size_t)(k0 + kr) * N + bn + nc);
            *(float4*)&Bs[kr][nc] = v;
        }
        __syncthreads();
#pragma unroll
        for (int kk = 0; kk < BK; ++kk) {
            float4 av = *(const float4*)&As[kk][ty * 4];
            float4 bv = *(const float4*)&Bs[kk][tx * 4];
            float a[4] = {av.x, av.y, av.z, av.w};
            float bb[4] = {bv.x, bv.y, bv.z, bv.w};
#pragma unroll
            for (int i = 0; i < 4; ++i)
#pragma unroll
                for (int j = 0; j < 4; ++j)
                    acc[i][j] = fmaf(a[i], bb[j], acc[i][j]);
        }
        __syncthreads();
    }
#pragma unroll
    for (int i = 0; i < 4; ++i) {
        int row = bm + ty * 4 + i;
        int col = bn + tx * 4;
        float4 o = make_float4(acc[i][0] + bias[col + 0], acc[i][1] + bias[col + 1],
                               acc[i][2] + bias[col + 2], acc[i][3] + bias[col + 3]);
        *(float4*)&C[(size_t)row * N + col] = o;
    }
}

// ---------------------------------------------------------------------------
// 4. LIF over T (used for final proj -> out; no packing)
__global__ __launch_bounds__(256) void lif_kernel(const float* src, float* dst, size_t stride) {
    size_t i = ((size_t)blockIdx.x * blockDim.x + threadIdx.x) * 4;
    float v[4] = {0.f, 0.f, 0.f, 0.f};
    for (int t = 0; t < TT; ++t) {
        float4 xv4 = *(const float4*)(src + (size_t)t * stride + i);
        float xv[4] = {xv4.x, xv4.y, xv4.z, xv4.w};
        float sp[4];
#pragma unroll
        for (int j = 0; j < 4; ++j) {
            v[j] = v[j] + (xv[j] - v[j]) * 0.5f;
            bool fire = (v[j] >= 1.0f);
            sp[j] = fire ? 1.0f : 0.0f;
            v[j] = fire ? 0.0f : v[j];
        }
        *(float4*)(dst + (size_t)t * stride + i) = make_float4(sp[0], sp[1], sp[2], sp[3]);
    }
}

// ---------------------------------------------------------------------------
// 4b. fused LIF + bit-pack over qkv. Block = one (b,l) row, 192 threads (4 c each).
//     Writes spike FLOATS only for the V third (c>=512; q/k floats unused
//     downstream). Packs q/k spike bits with a fixed intra-word permutation
//     (bit b <-> dim (b&7)*4 + (b>>3), same for q and k -> popc unchanged).
__global__ __launch_bounds__(192) void lif_pack_kernel(float* __restrict__ qkv,
                                                       uint32_t* __restrict__ pk) {
    int row = blockIdx.x;            // b*LL + l
    int tid = threadIdx.x;
    int c = tid * 4;
    int wid = tid >> 6;              // wave 0..2 (c-range: wid*256 .. +255)
    int lane = tid & 63;
    const size_t stride = (size_t)BB * LL * C3;
    float* base = qkv + (size_t)row * C3 + c;

    float v[4] = {0.f, 0.f, 0.f, 0.f};
    for (int t = 0; t < TT; ++t) {
        float4 xv4 = *(const float4*)(base + (size_t)t * stride);
        float xv[4] = {xv4.x, xv4.y, xv4.z, xv4.w};
        bool fire[4];
        float sp[4];
#pragma unroll
        for (int j = 0; j < 4; ++j) {
            v[j] = v[j] + (xv[j] - v[j]) * 0.5f;
            fire[j] = (v[j] >= 1.0f);
            sp[j] = fire[j] ? 1.0f : 0.0f;
            v[j] = fire[j] ? 0.0f : v[j];
        }
        if (c >= 512)   // V third: spikes consumed as floats by attn_pv
            *(float4*)(base + (size_t)t * stride) = make_float4(sp[0], sp[1], sp[2], sp[3]);
        // pack q/k bits (c < 512): word w covers dims [wave_base+32w, +32)
        unsigned long long B0 = __ballot(fire[0]);
        unsigned long long B1 = __ballot(fire[1]);
        unsigned long long B2 = __ballot(fire[2]);
        unsigned long long B3 = __ballot(fire[3]);
        if (lane < 8 && wid < 2) {
            uint32_t word = ((uint32_t)(B0 >> (8 * lane)) & 0xFFu)
                          | (((uint32_t)(B1 >> (8 * lane)) & 0xFFu) << 8)
                          | (((uint32_t)(B2 >> (8 * lane)) & 0xFFu) << 16)
                          | (((uint32_t)(B3 >> (8 * lane)) & 0xFFu) << 24);
            pk[((size_t)t * BB * LL + row) * 16 + wid * 8 + lane] = word;
        }
    }
}

// ---------------------------------------------------------------------------
// 5a. softmax stats: am, Z per (t,b,l,head). Block=(t,b,n,hp), 256 thr=(q,h).
__global__ __launch_bounds__(256) void attn_sm(const uint32_t* __restrict__ pk,
                                               const int* __restrict__ idxws,
                                               float2* __restrict__ amz) {
    int bid = blockIdx.x;
    int hp = bid & 3, n = (bid >> 2) & 7, b = (bid >> 5) & 3, t = bid >> 7;
    __shared__ uint32_t kbs[2][512];
    int tid = threadIdx.x;
    int q = tid & 127, h = tid >> 7;
    int lbase = (t * BB + b) * LL;

    const int* ip = idxws + (b * NWIN + n) * TOPKN;
    int s0r = ip[0], s1r = ip[1], s2r = ip[2], s3r = ip[3];

#pragma unroll 4
    for (int e = tid; e < 1024; e += 256) {
        int hh = e >> 9, kk = e & 511;
        int w = kk >> 7;
        int sw = (w == 0) ? s0r : (w == 1) ? s1r : (w == 2) ? s2r : s3r;
        int row = sw * WIN + (kk & 127);
        kbs[hh][kk] = pk[(size_t)(lbase + row) * 16 + 8 + hp * 2 + hh];
    }
    uint32_t qw = pk[(size_t)(lbase + n * WIN + q) * 16 + hp * 2 + h];
    __syncthreads();

    const float ALPHA_SC = 0.17677669529663687f;   // hd^-0.5
    const uint4* kb4 = (const uint4*)kbs[h];
    int smax = 0;
#pragma unroll 8
    for (int k4 = 0; k4 < 128; ++k4) {
        uint4 w4 = kb4[k4];
        smax = max(smax, __popc(qw & w4.x));
        smax = max(smax, __popc(qw & w4.y));
        smax = max(smax, __popc(qw & w4.z));
        smax = max(smax, __popc(qw & w4.w));
    }
    float am = __fmul_rn((float)smax, ALPHA_SC);
    float Z = 0.0f;
#pragma unroll 4
    for (int k4 = 0; k4 < 128; ++k4) {
        uint4 w4 = kb4[k4];
        Z += expf(__fsub_rn(__fmul_rn((float)__popc(qw & w4.x), ALPHA_SC), am));
        Z += expf(__fsub_rn(__fmul_rn((float)__popc(qw & w4.y), ALPHA_SC), am));
        Z += expf(__fsub_rn(__fmul_rn((float)__popc(qw & w4.z), ALPHA_SC), am));
        Z += expf(__fsub_rn(__fmul_rn((float)__popc(qw & w4.w), ALPHA_SC), am));
    }
    amz[(size_t)(lbase + n * WIN + q) * HH + hp * 2 + h] = make_float2(am, Z);
}

// ---------------------------------------------------------------------------
// 5b. PV v16: Block = (t,b,n,hp,h): 1024 blocks, 256 threads = (qg 0..63, dh 0..3).
//     Thread: q in {qg, qg+64} x 8 d (dh*8 slice): each broadcast b128 V read
//     feeds 16 fma (2x amortization of v15) at 4 waves/SIMD (2x v12's TLP).
//     V via global_load_lds DMA, 64-row halves double-buffered, counted vmcnt.
//     FP chains ascending k -> bitwise exact.
__global__ __launch_bounds__(256, 4) void attn_pv(const float* __restrict__ spk,
                                                  const uint32_t* __restrict__ pk,
                                                  const int* __restrict__ idxws,
                                                  const float2* __restrict__ amz,
                                                  float* __restrict__ out) {
    int bid = blockIdx.x;
    int h = bid & 1, hp = (bid >> 1) & 3, n = (bid >> 3) & 7, b = (bid >> 6) & 3, t = bid >> 8;
    __shared__ __align__(16) float Vlds[2][64][32];   // 2 x 8 KB half-window buffers
    __shared__ float ptab[33][WIN];                   // 16.9 KB
    __shared__ __align__(16) uint32_t kbs[4 * WIN];   // 2 KB (this h only)
    int tid = threadIdx.x;                            // 256 threads
    int qg = tid & 63, dh = tid >> 6;                 // dh 0..3 -> 8-dim slice
    int lbase = (t * BB + b) * LL;

    const int* ip = idxws + (b * NWIN + n) * TOPKN;
    int s0r = ip[0], s1r = ip[1], s2r = ip[2], s3r = ip[3];

    // stage gathered K bit-words (this h): 512 words, 2 per thread
#pragma unroll 2
    for (int e = tid; e < 512; e += 256) {
        int w = e >> 7;
        int sw = (w == 0) ? s0r : (w == 1) ? s1r : (w == 2) ? s2r : s3r;
        int row = sw * WIN + (e & 127);
        kbs[e] = pk[(size_t)(lbase + row) * 16 + 8 + hp * 2 + h];
    }
    uint32_t qw0 = pk[(size_t)(lbase + n * WIN + qg) * 16 + hp * 2 + h];
    uint32_t qw1 = pk[(size_t)(lbase + n * WIN + qg + 64) * 16 + hp * 2 + h];

    // V DMA geometry: per-lane global src; LDS dest = wave-uniform base + lane*16.
    const float* vsrc = spk + (size_t)lbase * C3 + 512 + hp * 64 + h * 32
                        + (size_t)(tid >> 3) * C3 + (tid & 7) * 4;
    int wvoff = (tid >> 6) * 1024;   // wave-uniform (wave id * 1 KB)

#define STAGE_HALF(hw_)                                                              \
    do {                                                                             \
        int hw = (hw_);                                                              \
        int ww = hw >> 1;                                                            \
        int sw = (ww == 0) ? s0r : (ww == 1) ? s1r : (ww == 2) ? s2r : s3r;          \
        const float* src = vsrc + (size_t)sw * (WIN * C3)                            \
                                + (size_t)(hw & 1) * 64 * C3;                        \
        char* lb = (char*)(&Vlds[hw & 1][0][0]) + wvoff;                             \
        __builtin_amdgcn_global_load_lds(                                            \
            (const __attribute__((address_space(1))) void*)src,                      \
            (__attribute__((address_space(3))) void*)lb, 16, 0, 0);                  \
        __builtin_amdgcn_global_load_lds(                                            \
            (const __attribute__((address_space(1))) void*)(src + 32 * C3),          \
            (__attribute__((address_space(3))) void*)(lb + 4096), 16, 0, 0);         \
    } while (0)

    STAGE_HALF(0);
    STAGE_HALF(1);

    // P table: threads 0..127 build column tid from (am,Z); hidden under DMA
    {
        if (tid < 128) {
            float2 az = amz[(size_t)(lbase + n * WIN + tid) * HH + hp * 2 + h];
            const float ALPHA_SC = 0.17677669529663687f;   // hd^-0.5
            for (int s = 0; s <= 32; ++s)
                ptab[s][tid] = expf(__fsub_rn(__fmul_rn((float)s, ALPHA_SC), az.x)) / az.y;
        }
    }

    float acc0[8], acc1[8];
#pragma unroll
    for (int d = 0; d < 8; ++d) { acc0[d] = 0.0f; acc1[d] = 0.0f; }

    asm volatile("s_waitcnt vmcnt(2)" ::: "memory");   // half0 done; half1 in flight
    __syncthreads();                                   // half0 + kbs + ptab visible

    const uint4* kb4 = (const uint4*)kbs;

#pragma unroll
    for (int hw = 0; hw < 8; ++hw) {
        // compute half hw: 16 groups of 4 rows, 2-row batches, ascending k
        const uint4* kw4 = kb4 + hw * 16;
        const float* vb = &Vlds[hw & 1][0][dh * 8];
#pragma unroll 2
        for (int g = 0; g < 16; ++g) {
            uint4 kw = kw4[g];
            const float* pr = vb + g * 128;
#pragma unroll
            for (int jp = 0; jp < 2; ++jp) {
                uint32_t ka = (jp == 0) ? kw.x : kw.z;
                uint32_t kb_ = (jp == 0) ? kw.y : kw.w;
                float Pa0 = ptab[__popc(qw0 & ka)][qg];
                float Pa1 = ptab[__popc(qw1 & ka)][qg + 64];
                float Pb0 = ptab[__popc(qw0 & kb_)][qg];
                float Pb1 = ptab[__popc(qw1 & kb_)][qg + 64];
                const float4* va = (const float4*)(pr + jp * 64);
                const float4* vbp = (const float4*)(pr + jp * 64 + 32);
                float4 a0 = va[0], a1 = va[1];
                float4 b0 = vbp[0], b1 = vbp[1];
                // row a (k even) then row b (k odd): per-chain ascending k
                acc0[0] = fmaf(Pa0, a0.x, acc0[0]);  acc1[0] = fmaf(Pa1, a0.x, acc1[0]);
                acc0[1] = fmaf(Pa0, a0.y, acc0[1]);  acc1[1] = fmaf(Pa1, a0.y, acc1[1]);
                acc0[2] = fmaf(Pa0, a0.z, acc0[2]);  acc1[2] = fmaf(Pa1, a0.z, acc1[2]);
                acc0[3] = fmaf(Pa0, a0.w, acc0[3]);  acc1[3] = fmaf(Pa1, a0.w, acc1[3]);
                acc0[4] = fmaf(Pa0, a1.x, acc0[4]);  acc1[4] = fmaf(Pa1, a1.x, acc1[4]);
                acc0[5] = fmaf(Pa0, a1.y, acc0[5]);  acc1[5] = fmaf(Pa1, a1.y, acc1[5]);
                acc0[6] = fmaf(Pa0, a1.z, acc0[6]);  acc1[6] = fmaf(Pa1, a1.z, acc1[6]);
                acc0[7] = fmaf(Pa0, a1.w, acc0[7]);  acc1[7] = fmaf(Pa1, a1.w, acc1[7]);
                acc0[0] = fmaf(Pb0, b0.x, acc0[0]);  acc1[0] = fmaf(Pb1, b0.x, acc1[0]);
                acc0[1] = fmaf(Pb0, b0.y, acc0[1]);  acc1[1] = fmaf(Pb1, b0.y, acc1[1]);
                acc0[2] = fmaf(Pb0, b0.z, acc0[2]);  acc1[2] = fmaf(Pb1, b0.z, acc1[2]);
                acc0[3] = fmaf(Pb0, b0.w, acc0[3]);  acc1[3] = fmaf(Pb1, b0.w, acc1[3]);
                acc0[4] = fmaf(Pb0, b1.x, acc0[4]);  acc1[4] = fmaf(Pb1, b1.x, acc1[4]);
                acc0[5] = fmaf(Pb0, b1.y, acc0[5]);  acc1[5] = fmaf(Pb1, b1.y, acc1[5]);
                acc0[6] = fmaf(Pb0, b1.z, acc0[6]);  acc1[6] = fmaf(Pb1, b1.z, acc1[6]);
                acc0[7] = fmaf(Pb0, b1.w, acc0[7]);  acc1[7] = fmaf(Pb1, b1.w, acc1[7]);
            }
        }

        if (hw < 7) {
            __syncthreads();              // all waves done reading buf[hw&1]
            if (hw < 6) {
                STAGE_HALF(hw + 2);       // refill buf[hw&1]
                asm volatile("s_waitcnt vmcnt(2)" ::: "memory");  // drain S(hw+1)
            } else {
                asm volatile("s_waitcnt vmcnt(0)" ::: "memory");  // drain S(7)
            }
            __syncthreads();              // half hw+1 visible to all waves
        }
    }
#undef STAGE_HALF

    size_t ob0 = (size_t)(lbase + n * WIN + qg) * CC + (hp * 2 + h) * 32 + dh * 8;
    size_t ob1 = ob0 + (size_t)64 * CC;
    *(float4*)&out[ob0]     = make_float4(acc0[0], acc0[1], acc0[2], acc0[3]);
    *(float4*)&out[ob0 + 4] = make_float4(acc0[4], acc0[5], acc0[6], acc0[7]);
    *(float4*)&out[ob1]     = make_float4(acc1[0], acc1[1], acc1[2], acc1[3]);
    *(float4*)&out[ob1 + 4] = make_float4(acc1[4], acc1[5], acc1[6], acc1[7]);
}

// ---------------------------------------------------------------------------
extern "C" void kernel_launch(void* const* d_in, const int* in_sizes, int n_in,
                              void* d_out, int out_size, void* d_ws, size_t ws_size,
                              hipStream_t stream) {
    const float* x      = (const float*)d_in[0];
    const float* w_qkv  = (const float*)d_in[1];
    const float* b_qkv  = (const float*)d_in[2];
    const float* w_proj = (const float*)d_in[3];
    const float* b_proj = (const float*)d_in[4];
    float* ws = (float*)d_ws;

    float* qkv      = ws;                 // 12582912 floats [T,B,L,3C] (V-third = spikes)
    float* attn_out = ws + 12582912;      // 4194304 floats [T,B,L,C]
    float* proj     = ws + 16777216;      // 4194304 floats [T,B,L,C]
    uint32_t* pkb   = (uint32_t*)proj;    // 262144 u32: aliases proj (dead before gemm_proj)
    float* region   = ws + 20971520;      // 8192 floats
    int*   idxp     = (int*)(ws + 20979712);  // 128 ints
    float2* amzp    = (float2*)(ws + 20979840); // 131072 float2 [T,B,L,H]
    float* outp     = (float*)d_out;

    region_kernel<<<dim3(BB * NWIN, 4), dim3(64), 0, stream>>>(x, region);
    route_kernel<<<dim3(BB), dim3(64), 0, stream>>>(region, idxp);
    gemm_bias128<<<dim3(128, 6), dim3(256), 0, stream>>>(x, w_qkv, b_qkv, qkv,
                                                         TT * BB * LL, C3, CC);
    lif_pack_kernel<<<dim3(BB * LL), dim3(192), 0, stream>>>(qkv, pkb);
    attn_sm<<<dim3(TT * BB * NWIN * 4), dim3(256), 0, stream>>>(pkb, idxp, amzp);
    attn_pv<<<dim3(TT * BB * NWIN * 4 * 2), dim3(256), 0, stream>>>(qkv, pkb, idxp, amzp, attn_out);
    gemm_bias64<<<dim3(256, 4), dim3(256), 0, stream>>>(attn_out, w_proj, b_proj, proj,
                                                        TT * BB * LL, CC, CC);
    lif_kernel<<<dim3(1024), dim3(256), 0, stream>>>(proj, outp, (size_t)BB * LL * CC);
}

// Round 17
// 245.915 us; speedup vs baseline: 2.3432x; 1.0628x over previous
//
#include <hip/hip_runtime.h>
#include <cstdint>
#include <cstddef>

#define TT 4
#define BB 4
#define LL 1024
#define CC 256
#define HH 8
#define HD 32
#define NWIN 8
#define WIN 128
#define TOPKN 4
#define C3 768

// ---------------------------------------------------------------------------
// 1. region sums: c-split over 4 blocks (per-c (t,r) chain order unchanged)
__global__ __launch_bounds__(64) void region_kernel(const float* __restrict__ x,
                                                    float* __restrict__ region) {
    int bn = blockIdx.x;          // b*NWIN + n
    int b = bn >> 3, n = bn & 7;
    int c = blockIdx.y * 64 + threadIdx.x;
    float tot = 0.0f;
    for (int r = 0; r < WIN; ++r) {
        int l = n * WIN + r;
        float s = 0.0f;
        for (int t = 0; t < TT; ++t) {
            s += x[(((size_t)t * BB + b) * LL + l) * CC + c];
        }
        tot += s;
    }
    region[(size_t)bn * CC + c] = tot;
}

// ---------------------------------------------------------------------------
// 2. routing
__global__ __launch_bounds__(64) void route_kernel(const float* __restrict__ region,
                                                   int* __restrict__ idx) {
    int b = blockIdx.x;
    __shared__ float reg[NWIN][CC];
    __shared__ float attn_r[NWIN][NWIN];
    int tid = threadIdx.x;
    for (int e = tid; e < NWIN * CC; e += 64)
        reg[e >> 8][e & 255] = region[(size_t)b * NWIN * CC + e];
    __syncthreads();
    int n = tid >> 3, m = tid & 7;
    float s = 0.0f;
    for (int c = 0; c < CC; ++c) s += reg[n][c] * reg[m][c];
    attn_r[n][m] = s * 0.0625f;   // C^-0.5 = 1/16 exact
    __syncthreads();
    if (tid < NWIN) {
        float vals[NWIN];
        for (int m2 = 0; m2 < NWIN; ++m2) vals[m2] = attn_r[tid][m2];
        for (int kk = 0; kk < TOPKN; ++kk) {
            int bi = 0; float bv = vals[0];
            for (int m2 = 1; m2 < NWIN; ++m2) {
                if (vals[m2] > bv) { bv = vals[m2]; bi = m2; }
            }
            idx[(b * NWIN + tid) * TOPKN + kk] = bi;
            vals[bi] = -INFINITY;
        }
    }
}

// ---------------------------------------------------------------------------
// 3a. fp32 GEMM + bias, 128x128 tile (qkv), conflict-free B reads.
__global__ __launch_bounds__(256, 3) void gemm_bias128(const float* __restrict__ A,
                                                       const float* __restrict__ W,
                                                       const float* __restrict__ bias,
                                                       float* __restrict__ C,
                                                       int M, int N, int K) {
    const int BM = 128, BN = 128, BK = 16, TM = 8;
    __shared__ float As[BK][BM + 4];
    __shared__ float Bs[BK][136];
    int tid = threadIdx.x;
    int tx = tid & 15, ty = tid >> 4;
    int bm = blockIdx.x * BM, bn = blockIdx.y * BN;
    float acc[TM][8] = {};
    for (int k0 = 0; k0 < K; k0 += BK) {
#pragma unroll
        for (int it = 0; it < 2; ++it) {
            int i = it * 256 + tid;
            int row = i >> 2, kc = (i & 3) * 4;
            float4 v = *(const float4*)(A + (size_t)(bm + row) * K + k0 + kc);
            As[kc + 0][row] = v.x; As[kc + 1][row] = v.y;
            As[kc + 2][row] = v.z; As[kc + 3][row] = v.w;
        }
#pragma unroll
        for (int it = 0; it < 2; ++it) {
            int i = it * 256 + tid;
            int kr = i >> 5, nc = (i & 31) * 4;
            float4 v = *(const float4*)(W + (size_t)(k0 + kr) * N + bn + nc);
            *(float4*)&Bs[kr][nc] = v;
        }
        __syncthreads();
#pragma unroll
        for (int kk = 0; kk < BK; ++kk) {
            float a[TM], bb[8];
            const float4* ap = (const float4*)&As[kk][ty * TM];
            float4 a0 = ap[0], a1 = ap[1];
            a[0]=a0.x; a[1]=a0.y; a[2]=a0.z; a[3]=a0.w;
            a[4]=a1.x; a[5]=a1.y; a[6]=a1.z; a[7]=a1.w;
            float4 b0 = *(const float4*)&Bs[kk][tx * 4];
            float4 b1 = *(const float4*)&Bs[kk][64 + tx * 4];
            bb[0]=b0.x; bb[1]=b0.y; bb[2]=b0.z; bb[3]=b0.w;
            bb[4]=b1.x; bb[5]=b1.y; bb[6]=b1.z; bb[7]=b1.w;
#pragma unroll
            for (int i = 0; i < TM; ++i)
#pragma unroll
                for (int j = 0; j < 8; ++j)
                    acc[i][j] = fmaf(a[i], bb[j], acc[i][j]);
        }
        __syncthreads();
    }
#pragma unroll
    for (int i = 0; i < TM; ++i) {
        int row = bm + ty * TM + i;
        int col0 = bn + tx * 4;
        int col1 = bn + 64 + tx * 4;
        float4 o0 = make_float4(acc[i][0] + bias[col0 + 0], acc[i][1] + bias[col0 + 1],
                                acc[i][2] + bias[col0 + 2], acc[i][3] + bias[col0 + 3]);
        float4 o1 = make_float4(acc[i][4] + bias[col1 + 0], acc[i][5] + bias[col1 + 1],
                                acc[i][6] + bias[col1 + 2], acc[i][7] + bias[col1 + 3]);
        *(float4*)&C[(size_t)row * N + col0] = o0;
        *(float4*)&C[(size_t)row * N + col1] = o1;
    }
}

// ---------------------------------------------------------------------------
// 3b. fp32 GEMM + bias, 64x64 tile (proj)
__global__ __launch_bounds__(256, 4) void gemm_bias64(const float* __restrict__ A,
                                                      const float* __restrict__ W,
                                                      const float* __restrict__ bias,
                                                      float* __restrict__ C,
                                                      int M, int N, int K) {
    const int BM = 64, BN = 64, BK = 16;
    __shared__ float As[BK][BM + 4];
    __shared__ float Bs[BK][72];
    int tid = threadIdx.x;
    int tx = tid & 15, ty = tid >> 4;
    int bm = blockIdx.x * BM, bn = blockIdx.y * BN;
    float acc[4][4] = {};
    for (int k0 = 0; k0 < K; k0 += BK) {
        {
            int row = tid >> 2, kc = (tid & 3) * 4;
            float4 v = *(const float4*)(A + (size_t)(bm + row) * K + k0 + kc);
            As[kc + 0][row] = v.x; As[kc + 1][row] = v.y;
            As[kc + 2][row] = v.z; As[kc + 3][row] = v.w;
        }
        {
            int kr = tid >> 4, nc = (tid & 15) * 4;
            float4 v = *(const float4*)(W + (size_t)(k0 + kr) * N + bn + nc);
            *(float4*)&Bs[kr][nc] = v;
        }
        __syncthreads();
#pragma unroll
        for (int kk = 0; kk < BK; ++kk) {
            float4 av = *(const float4*)&As[kk][ty * 4];
            float4 bv = *(const float4*)&Bs[kk][tx * 4];
            float a[4] = {av.x, av.y, av.z, av.w};
            float bb[4] = {bv.x, bv.y, bv.z, bv.w};
#pragma unroll
            for (int i = 0; i < 4; ++i)
#pragma unroll
                for (int j = 0; j < 4; ++j)
                    acc[i][j] = fmaf(a[i], bb[j], acc[i][j]);
        }
        __syncthreads();
    }
#pragma unroll
    for (int i = 0; i < 4; ++i) {
        int row = bm + ty * 4 + i;
        int col = bn + tx * 4;
        float4 o = make_float4(acc[i][0] + bias[col + 0], acc[i][1] + bias[col + 1],
                               acc[i][2] + bias[col + 2], acc[i][3] + bias[col + 3]);
        *(float4*)&C[(size_t)row * N + col] = o;
    }
}

// ---------------------------------------------------------------------------
// 4. LIF over T (final proj -> out)
__global__ __launch_bounds__(256) void lif_kernel(const float* src, float* dst, size_t stride) {
    size_t i = ((size_t)blockIdx.x * blockDim.x + threadIdx.x) * 4;
    float v[4] = {0.f, 0.f, 0.f, 0.f};
    for (int t = 0; t < TT; ++t) {
        float4 xv4 = *(const float4*)(src + (size_t)t * stride + i);
        float xv[4] = {xv4.x, xv4.y, xv4.z, xv4.w};
        float sp[4];
#pragma unroll
        for (int j = 0; j < 4; ++j) {
            v[j] = v[j] + (xv[j] - v[j]) * 0.5f;
            bool fire = (v[j] >= 1.0f);
            sp[j] = fire ? 1.0f : 0.0f;
            v[j] = fire ? 0.0f : v[j];
        }
        *(float4*)(dst + (size_t)t * stride + i) = make_float4(sp[0], sp[1], sp[2], sp[3]);
    }
}

// ---------------------------------------------------------------------------
// 4b. fused LIF + bit-pack over qkv (q/k thirds packed; V third spike floats)
__global__ __launch_bounds__(192) void lif_pack_kernel(float* __restrict__ qkv,
                                                       uint32_t* __restrict__ pk) {
    int row = blockIdx.x;            // b*LL + l
    int tid = threadIdx.x;
    int c = tid * 4;
    int wid = tid >> 6;              // wave 0..2 (c-range: wid*256 .. +255)
    int lane = tid & 63;
    const size_t stride = (size_t)BB * LL * C3;
    float* base = qkv + (size_t)row * C3 + c;

    float v[4] = {0.f, 0.f, 0.f, 0.f};
    for (int t = 0; t < TT; ++t) {
        float4 xv4 = *(const float4*)(base + (size_t)t * stride);
        float xv[4] = {xv4.x, xv4.y, xv4.z, xv4.w};
        bool fire[4];
        float sp[4];
#pragma unroll
        for (int j = 0; j < 4; ++j) {
            v[j] = v[j] + (xv[j] - v[j]) * 0.5f;
            fire[j] = (v[j] >= 1.0f);
            sp[j] = fire[j] ? 1.0f : 0.0f;
            v[j] = fire[j] ? 0.0f : v[j];
        }
        if (c >= 512)   // V third: spikes consumed as floats by attn_pv
            *(float4*)(base + (size_t)t * stride) = make_float4(sp[0], sp[1], sp[2], sp[3]);
        unsigned long long B0 = __ballot(fire[0]);
        unsigned long long B1 = __ballot(fire[1]);
        unsigned long long B2 = __ballot(fire[2]);
        unsigned long long B3 = __ballot(fire[3]);
        if (lane < 8 && wid < 2) {
            uint32_t word = ((uint32_t)(B0 >> (8 * lane)) & 0xFFu)
                          | (((uint32_t)(B1 >> (8 * lane)) & 0xFFu) << 8)
                          | (((uint32_t)(B2 >> (8 * lane)) & 0xFFu) << 16)
                          | (((uint32_t)(B3 >> (8 * lane)) & 0xFFu) << 24);
            pk[((size_t)t * BB * LL + row) * 16 + wid * 8 + lane] = word;
        }
    }
}

// ---------------------------------------------------------------------------
// 5. fused sm+PV v17. Block = (t,b,n,hp,h): 1024 blocks, 256 threads = (qg, dh).
//    sm fused via table: threads 0..127 (q = tid) compute smax -> am, store
//    expf terms into ptab column, sum Z from the STORED values (ascending k,
//    bitwise == direct expf sum), divide column in place. PV: 2q x 8d/thread.
//    RAW s_barrier + counted vmcnt(2) -> DMA truly async (no __syncthreads drain).
__global__ __launch_bounds__(256, 4) void attn_pv(const float* __restrict__ spk,
                                                  const uint32_t* __restrict__ pk,
                                                  const int* __restrict__ idxws,
                                                  float* __restrict__ out) {
    int bid = blockIdx.x;
    int h = bid & 1, hp = (bid >> 1) & 3, n = (bid >> 3) & 7, b = (bid >> 6) & 3, t = bid >> 8;
    __shared__ __align__(16) float Vlds[2][64][32];   // 2 x 8 KB half-window buffers
    __shared__ float ptab[33][WIN];                   // 16.9 KB
    __shared__ __align__(16) uint32_t kbs[4 * WIN];   // 2 KB (this h only)
    int tid = threadIdx.x;                            // 256 threads
    int qg = tid & 63, dh = tid >> 6;                 // dh 0..3 -> 8-dim slice
    int lbase = (t * BB + b) * LL;

    const int* ip = idxws + (b * NWIN + n) * TOPKN;
    int s0r = ip[0], s1r = ip[1], s2r = ip[2], s3r = ip[3];

    // stage gathered K bit-words (this h): 512 words, 2 per thread
#pragma unroll 2
    for (int e = tid; e < 512; e += 256) {
        int w = e >> 7;
        int sw = (w == 0) ? s0r : (w == 1) ? s1r : (w == 2) ? s2r : s3r;
        int row = sw * WIN + (e & 127);
        kbs[e] = pk[(size_t)(lbase + row) * 16 + 8 + hp * 2 + h];
    }
    uint32_t qw0 = pk[(size_t)(lbase + n * WIN + qg) * 16 + hp * 2 + h];
    uint32_t qw1 = pk[(size_t)(lbase + n * WIN + qg + 64) * 16 + hp * 2 + h];

    // V DMA geometry: per-lane global src; LDS dest = wave-uniform base + lane*16.
    const float* vsrc = spk + (size_t)lbase * C3 + 512 + hp * 64 + h * 32
                        + (size_t)(tid >> 3) * C3 + (tid & 7) * 4;
    int wvoff = (tid >> 6) * 1024;   // wave-uniform (wave id * 1 KB)

#define STAGE_HALF(hw_)                                                              \
    do {                                                                             \
        int hw = (hw_);                                                              \
        int ww = hw >> 1;                                                            \
        int sw = (ww == 0) ? s0r : (ww == 1) ? s1r : (ww == 2) ? s2r : s3r;          \
        const float* src = vsrc + (size_t)sw * (WIN * C3)                            \
                                + (size_t)(hw & 1) * 64 * C3;                        \
        char* lb = (char*)(&Vlds[hw & 1][0][0]) + wvoff;                             \
        __builtin_amdgcn_global_load_lds(                                            \
            (const __attribute__((address_space(1))) void*)src,                      \
            (__attribute__((address_space(3))) void*)lb, 16, 0, 0);                  \
        __builtin_amdgcn_global_load_lds(                                            \
            (const __attribute__((address_space(1))) void*)(src + 32 * C3),          \
            (__attribute__((address_space(3))) void*)(lb + 4096), 16, 0, 0);         \
    } while (0)

    STAGE_HALF(0);
    STAGE_HALF(1);

    // kbs visible to all (raw barrier: DMA keeps flying)
    asm volatile("s_waitcnt lgkmcnt(0)" ::: "memory");
    __builtin_amdgcn_s_barrier();

    // ---- fused softmax stats for q = tid (threads 0..127), table-ized:
    const float ALPHA_SC = 0.17677669529663687f;   // hd^-0.5
    const uint4* kb4 = (const uint4*)kbs;
    if (tid < 128) {
        uint32_t qwt = (tid & 64) ? qw1 : qw0;     // q == tid
        int smax = 0;
#pragma unroll 8
        for (int k4 = 0; k4 < 128; ++k4) {
            uint4 w4 = kb4[k4];
            smax = max(smax, __popc(qwt & w4.x));
            smax = max(smax, __popc(qwt & w4.y));
            smax = max(smax, __popc(qwt & w4.z));
            smax = max(smax, __popc(qwt & w4.w));
        }
        float am = __fmul_rn((float)smax, ALPHA_SC);
        // store the 33 expf terms (exact values of expf(fl(s*alpha)-am))
        for (int s = 0; s <= 32; ++s)
            ptab[s][tid] = expf(__fsub_rn(__fmul_rn((float)s, ALPHA_SC), am));
        // Z = ascending-k sum of the STORED terms (bitwise == expf-sum)
        float Z = 0.0f;
#pragma unroll 4
        for (int k4 = 0; k4 < 128; ++k4) {
            uint4 w4 = kb4[k4];
            Z += ptab[__popc(qwt & w4.x)][tid];
            Z += ptab[__popc(qwt & w4.y)][tid];
            Z += ptab[__popc(qwt & w4.z)][tid];
            Z += ptab[__popc(qwt & w4.w)][tid];
        }
        // in-place divide: expf(...)/Z with identical operands
        for (int s = 0; s <= 32; ++s)
            ptab[s][tid] = ptab[s][tid] / Z;
    }

    float acc0[8], acc1[8];
#pragma unroll
    for (int d = 0; d < 8; ++d) { acc0[d] = 0.0f; acc1[d] = 0.0f; }

    // ptab writes drained; half0 DMA complete (half1 still in flight)
    asm volatile("s_waitcnt lgkmcnt(0)" ::: "memory");
    asm volatile("s_waitcnt vmcnt(2)" ::: "memory");
    __builtin_amdgcn_s_barrier();

#pragma unroll
    for (int hw = 0; hw < 8; ++hw) {
        // compute half hw: 16 groups of 4 rows, 2-row batches, ascending k
        const uint4* kw4 = kb4 + hw * 16;
        const float* vb = &Vlds[hw & 1][0][dh * 8];
#pragma unroll 2
        for (int g = 0; g < 16; ++g) {
            uint4 kw = kw4[g];
            const float* pr = vb + g * 128;
#pragma unroll
            for (int jp = 0; jp < 2; ++jp) {
                uint32_t ka = (jp == 0) ? kw.x : kw.z;
                uint32_t kb_ = (jp == 0) ? kw.y : kw.w;
                float Pa0 = ptab[__popc(qw0 & ka)][qg];
                float Pa1 = ptab[__popc(qw1 & ka)][qg + 64];
                float Pb0 = ptab[__popc(qw0 & kb_)][qg];
                float Pb1 = ptab[__popc(qw1 & kb_)][qg + 64];
                const float4* va = (const float4*)(pr + jp * 64);
                const float4* vbp = (const float4*)(pr + jp * 64 + 32);
                float4 a0 = va[0], a1 = va[1];
                float4 b0 = vbp[0], b1 = vbp[1];
                acc0[0] = fmaf(Pa0, a0.x, acc0[0]);  acc1[0] = fmaf(Pa1, a0.x, acc1[0]);
                acc0[1] = fmaf(Pa0, a0.y, acc0[1]);  acc1[1] = fmaf(Pa1, a0.y, acc1[1]);
                acc0[2] = fmaf(Pa0, a0.z, acc0[2]);  acc1[2] = fmaf(Pa1, a0.z, acc1[2]);
                acc0[3] = fmaf(Pa0, a0.w, acc0[3]);  acc1[3] = fmaf(Pa1, a0.w, acc1[3]);
                acc0[4] = fmaf(Pa0, a1.x, acc0[4]);  acc1[4] = fmaf(Pa1, a1.x, acc1[4]);
                acc0[5] = fmaf(Pa0, a1.y, acc0[5]);  acc1[5] = fmaf(Pa1, a1.y, acc1[5]);
                acc0[6] = fmaf(Pa0, a1.z, acc0[6]);  acc1[6] = fmaf(Pa1, a1.z, acc1[6]);
                acc0[7] = fmaf(Pa0, a1.w, acc0[7]);  acc1[7] = fmaf(Pa1, a1.w, acc1[7]);
                acc0[0] = fmaf(Pb0, b0.x, acc0[0]);  acc1[0] = fmaf(Pb1, b0.x, acc1[0]);
                acc0[1] = fmaf(Pb0, b0.y, acc0[1]);  acc1[1] = fmaf(Pb1, b0.y, acc1[1]);
                acc0[2] = fmaf(Pb0, b0.z, acc0[2]);  acc1[2] = fmaf(Pb1, b0.z, acc1[2]);
                acc0[3] = fmaf(Pb0, b0.w, acc0[3]);  acc1[3] = fmaf(Pb1, b0.w, acc1[3]);
                acc0[4] = fmaf(Pb0, b1.x, acc0[4]);  acc1[4] = fmaf(Pb1, b1.x, acc1[4]);
                acc0[5] = fmaf(Pb0, b1.y, acc0[5]);  acc1[5] = fmaf(Pb1, b1.y, acc1[5]);
                acc0[6] = fmaf(Pb0, b1.z, acc0[6]);  acc1[6] = fmaf(Pb1, b1.z, acc1[6]);
                acc0[7] = fmaf(Pb0, b1.w, acc0[7]);  acc1[7] = fmaf(Pb1, b1.w, acc1[7]);
            }
        }

        if (hw < 7) {
            __builtin_amdgcn_s_barrier();     // all waves done reading buf[hw&1]
            if (hw < 6) {
                STAGE_HALF(hw + 2);           // refill buf[hw&1] (async)
                asm volatile("s_waitcnt vmcnt(2)" ::: "memory");  // S(hw+1) done
            } else {
                asm volatile("s_waitcnt vmcnt(0)" ::: "memory");  // S(7) done
            }
            __builtin_amdgcn_s_barrier();     // half hw+1 visible to all waves
        }
    }
#undef STAGE_HALF

    size_t ob0 = (size_t)(lbase + n * WIN + qg) * CC + (hp * 2 + h) * 32 + dh * 8;
    size_t ob1 = ob0 + (size_t)64 * CC;
    *(float4*)&out[ob0]     = make_float4(acc0[0], acc0[1], acc0[2], acc0[3]);
    *(float4*)&out[ob0 + 4] = make_float4(acc0[4], acc0[5], acc0[6], acc0[7]);
    *(float4*)&out[ob1]     = make_float4(acc1[0], acc1[1], acc1[2], acc1[3]);
    *(float4*)&out[ob1 + 4] = make_float4(acc1[4], acc1[5], acc1[6], acc1[7]);
}

// ---------------------------------------------------------------------------
extern "C" void kernel_launch(void* const* d_in, const int* in_sizes, int n_in,
                              void* d_out, int out_size, void* d_ws, size_t ws_size,
                              hipStream_t stream) {
    const float* x      = (const float*)d_in[0];
    const float* w_qkv  = (const float*)d_in[1];
    const float* b_qkv  = (const float*)d_in[2];
    const float* w_proj = (const float*)d_in[3];
    const float* b_proj = (const float*)d_in[4];
    float* ws = (float*)d_ws;

    float* qkv      = ws;                 // 12582912 floats [T,B,L,3C] (V-third = spikes)
    float* attn_out = ws + 12582912;      // 4194304 floats [T,B,L,C]
    float* proj     = ws + 16777216;      // 4194304 floats [T,B,L,C]
    uint32_t* pkb   = (uint32_t*)proj;    // 262144 u32: aliases proj (dead before gemm_proj)
    float* region   = ws + 20971520;      // 8192 floats
    int*   idxp     = (int*)(ws + 20979712);  // 128 ints
    float* outp     = (float*)d_out;

    region_kernel<<<dim3(BB * NWIN, 4), dim3(64), 0, stream>>>(x, region);
    route_kernel<<<dim3(BB), dim3(64), 0, stream>>>(region, idxp);
    gemm_bias128<<<dim3(128, 6), dim3(256), 0, stream>>>(x, w_qkv, b_qkv, qkv,
                                                         TT * BB * LL, C3, CC);
    lif_pack_kernel<<<dim3(BB * LL), dim3(192), 0, stream>>>(qkv, pkb);
    attn_pv<<<dim3(TT * BB * NWIN * 4 * 2), dim3(256), 0, stream>>>(qkv, pkb, idxp, attn_out);
    gemm_bias64<<<dim3(256, 4), dim3(256), 0, stream>>>(attn_out, w_proj, b_proj, proj,
                                                        TT * BB * LL, CC, CC);
    lif_kernel<<<dim3(1024), dim3(256), 0, stream>>>(proj, outp, (size_t)BB * LL * CC);
}